// Round 8
// baseline (458.238 us; speedup 1.0000x reference)
//
#include <hip/hip_runtime.h>
#include <stdint.h>

#define Q_MAX_F 127.0f
#define EPS_F 1e-7f

typedef int   v4i  __attribute__((ext_vector_type(4)));
typedef int   v16i __attribute__((ext_vector_type(16)));
typedef float v4f  __attribute__((ext_vector_type(4)));

// ---------------------------------------------------------------------------
// Fragment layouts (16B "chunk" = 16 int8 along K), KT = K/64 K-tiles.
// xq (A): row -> rb=row>>7, fi=(row>>5)&3, cl=row&31 ; k16 -> kt=k16>>2,
//         ks=(k16>>1)&1, ch=k16&1
//   chunk index = (((rb*KT + kt)*2 + ks)*4 + fi)*64 + ch*32 + cl
//   -> GEMM wave (panel rb) loads a[ks][fi] as ONE contiguous 1KB at lane*16.
// wq (B): col n -> cb=n>>6, fj=(n>>5)&1, cl=n&31 ; same k16 split
//   chunk index = (((cb*KT + kt)*2 + ks)*2 + fj)*64 + ch*32 + cl
//   -> staging linear->linear; ds_read lane-linear (conflict-free).
// ---------------------------------------------------------------------------

// Kernel 1: per-row dynamic quant of x -> xq in fragment layout.
__global__ __launch_bounds__(256) void quant_x_kernel(
    const float* __restrict__ x, int8_t* __restrict__ xq,
    float* __restrict__ xscale, int M, int K, int QB) {
  const int t = threadIdx.x;
  const int KT = K >> 6;
  __shared__ float sm[4];
  for (int row = blockIdx.x; row < M; row += QB) {
    const float* xr = x + (size_t)row * K + t * 16;
    float v[16];
    float m = 0.f;
#pragma unroll
    for (int c = 0; c < 4; ++c) {
      v4f f = *(const v4f*)(xr + c * 4);
#pragma unroll
      for (int j = 0; j < 4; ++j) {
        v[c * 4 + j] = f[j];
        m = fmaxf(m, fabsf(f[j]));
      }
    }
#pragma unroll
    for (int off = 32; off; off >>= 1) m = fmaxf(m, __shfl_xor(m, off));
    if ((t & 63) == 0) sm[t >> 6] = m;
    __syncthreads();
    m = fmaxf(fmaxf(sm[0], sm[1]), fmaxf(sm[2], sm[3]));
    __syncthreads();  // protect sm[] reuse on next row iteration
    const float s = fmaxf(m, EPS_F) / Q_MAX_F;
    const float inv = 1.0f / s;
    if (t == 0) xscale[row] = s;
    v4i pk;
#pragma unroll
    for (int c = 0; c < 4; ++c) {
      int pw = 0;
#pragma unroll
      for (int j = 0; j < 4; ++j) {
        float q = rintf(v[c * 4 + j] * inv);  // RNE; matches jnp.round
        q = fminf(fmaxf(q, -127.f), 127.f);
        pw |= ((int)q & 0xff) << (8 * j);
      }
      pk[c] = pw;
    }
    const int rb = row >> 7, f2 = (row >> 5) & 3, cl = row & 31;
    const int kt = t >> 2, ks = (t >> 1) & 1, ch = t & 1;
    const size_t flat =
        ((((size_t)rb * KT + kt) * 2 + ks) * 4 + f2) * 64 + ch * 32 + cl;
    *(v4i*)(xq + flat * 16) = pk;
  }
}

// Kernel 2: pack w (int32) -> wq int8 in fragment layout (output-ordered:
// writes coalesced; each lane reads its own 64B row-segment).
__global__ __launch_bounds__(256) void pack_w_kernel(
    const int* __restrict__ w, int8_t* __restrict__ wq, int K, long nchunks) {
  const int KT = K >> 6;
  const long stride = (long)gridDim.x * 256;
  for (long o = (long)blockIdx.x * 256 + threadIdx.x; o < nchunks;
       o += stride) {
    const int cl = (int)(o & 31);
    const int ch = (int)((o >> 5) & 1);
    const int fj = (int)((o >> 6) & 1);
    const int ks = (int)((o >> 7) & 1);
    const long rest = o >> 8;
    const int kt = (int)(rest & (KT - 1));  // KT is a power of two here
    const long cb = rest >> 6;              // == rest / KT for KT=64
    const long n = cb * 64 + fj * 32 + cl;
    const long k16 = (long)kt * 4 + ks * 2 + ch;
    const int* src = w + n * K + k16 * 16;
    v4i outw;
#pragma unroll
    for (int c = 0; c < 4; ++c) {
      v4i a = *(const v4i*)(src + c * 4);
      outw[c] = (a[0] & 0xff) | ((a[1] & 0xff) << 8) |
                ((a[2] & 0xff) << 16) | ((a[3] & 0xff) << 24);
    }
    *(v4i*)(wq + o * 16) = outw;
  }
}

// ---------------------------------------------------------------------------
// Kernel 3: int8 GEMM. A streamed global->reg (fragment layout, L1/L2-served),
// B staged in LDS (fragment layout, all-linear -> zero bank conflicts).
// 256x256 tile, 8 waves (2Mx4N), wave 128x64 = 4x2 frags of 32x32, BK=64B.
// 4-slot B rotation (64KB LDS), stage kt+3; A regs double-buffered via
// unroll-x2 with named sets (no runtime indexing -> no scratch).
// ONE barrier + counted vmcnt per kt. Fused dequant+bias epilogue.
// ---------------------------------------------------------------------------
#define BMg 256
#define BNg 256

__global__ __launch_bounds__(512, 2) void w8a8_gemm_kernel(
    const int8_t* __restrict__ xq, const int8_t* __restrict__ wq,
    const float* __restrict__ xscale, const float* __restrict__ wscale,
    const float* __restrict__ bias, float* __restrict__ out,
    int M, int N, int K) {
  __shared__ __align__(16) char lds[65536];  // 4 slots x 16KB (B only)

  const int t = threadIdx.x;
  const int lane = t & 63;
  const int wid = t >> 6;     // 0..7
  const int wr = wid >> 2;    // 0..1 -> rows [wr*128, +128)
  const int wc = wid & 3;     // 0..3 -> cols [wc*64, +64)

  const int nwg = gridDim.x;
  int bid = blockIdx.x;
  // XCD swizzle: 16 consecutive wg (same bm) land on one XCD -> the A panel
  // is L2-resident and shared by co-resident blocks.
  int wg = ((nwg & 7) == 0) ? ((bid & 7) * (nwg >> 3) + (bid >> 3)) : bid;

  const int nbn = N / BNg;
  const int bm = (wg / nbn) * BMg;
  const int bn = (wg % nbn) * BNg;

  const int KT = K >> 6;
  const int NT = KT;

  const char* aBase = (const char*)xq +
                      ((size_t)((bm >> 7) + wr) * KT) * 8192 +
                      (size_t)lane * 16;
  const char* bBase = (const char*)wq + ((size_t)(bn >> 6) * KT) * 4096;

  v16i acc[4][2] = {};
  v4i aA[2][4], aB[2][4];

  auto loadA = [&](v4i (*dst)[4], int kt) {
    const char* p = aBase + (size_t)kt * 8192;
#pragma unroll
    for (int ks = 0; ks < 2; ++ks)
#pragma unroll
      for (int fi = 0; fi < 4; ++fi)
        dst[ks][fi] = *(const v4i*)(p + (ks * 4 + fi) * 1024);
  };
  auto stageB = [&](int kt) {
#pragma unroll
    for (int i = 0; i < 2; ++i) {
      const int q = wid * 2 + i;  // strip s=q>>2, piece=q&3=(ks*2+fj)
      const char* src = bBase + ((size_t)(q >> 2) * KT + kt) * 4096 +
                        (q & 3) * 1024 + (size_t)lane * 16;
      __builtin_amdgcn_global_load_lds(
          (const __attribute__((address_space(1))) void*)src,
          (__attribute__((address_space(3))) void*)(lds + (kt & 3) * 16384 +
                                                    q * 1024),
          16, 0, 0);
    }
  };

  auto body = [&](int kt, v4i (*cur)[4], v4i (*nxt)[4]) {
    if (kt + 1 < NT) loadA(nxt, kt + 1);
    if (kt + 3 < NT) stageB(kt + 3);
    const char* slot = lds + (kt & 3) * 16384 + wc * 4096 + (size_t)lane * 16;
    v4i bfr[2][2];
#pragma unroll
    for (int ks = 0; ks < 2; ++ks)
#pragma unroll
      for (int fj = 0; fj < 2; ++fj)
        bfr[ks][fj] = *(const v4i*)(slot + (ks * 2 + fj) * 1024);
    __builtin_amdgcn_s_setprio(1);
#pragma unroll
    for (int ks = 0; ks < 2; ++ks)
#pragma unroll
      for (int fi = 0; fi < 4; ++fi)
#pragma unroll
        for (int fj = 0; fj < 2; ++fj)
          acc[fi][fj] = __builtin_amdgcn_mfma_i32_32x32x32_i8(
              cur[ks][fi], bfr[ks][fj], acc[fi][fj], 0, 0, 0);
    __builtin_amdgcn_s_setprio(0);
    if (kt + 1 < NT) {
      // FIFO at this point: [B(kt+2), A(kt+1), B(kt+3)] -> vmcnt(2) leaves
      // B(kt+3) in flight while guaranteeing A(kt+1), B(kt+1..2) landed.
      if (kt + 3 < NT) asm volatile("s_waitcnt vmcnt(2)" ::: "memory");
      else             asm volatile("s_waitcnt vmcnt(0)" ::: "memory");
      asm volatile("s_barrier" ::: "memory");
    }
  };

  loadA(aA, 0);
  stageB(0); stageB(1); stageB(2);
  asm volatile("s_waitcnt vmcnt(4)" ::: "memory");  // A(0)+B(0) done
  asm volatile("s_barrier" ::: "memory");

  for (int kt = 0; kt < NT; kt += 2) {
    body(kt, aA, aB);
    body(kt + 1, aB, aA);
  }

  // Epilogue. 32x32 C/D: col = lane&31, row = (reg&3)+8*(reg>>2)+4*(lane>>5).
  const int cl = lane & 31;
  const int hl = lane >> 5;
  const float wsc0 = wscale[bn + wc * 64 + cl];
  const float wsc1 = wscale[bn + wc * 64 + 32 + cl];
  const float bs0 = bias[bn + wc * 64 + cl];
  const float bs1 = bias[bn + wc * 64 + 32 + cl];
#pragma unroll
  for (int fi = 0; fi < 4; ++fi) {
#pragma unroll
    for (int r = 0; r < 16; ++r) {
      const int grow = bm + wr * 128 + fi * 32 + (r & 3) + 8 * (r >> 2) + 4 * hl;
      const float xs = xscale[grow];
      float* orow = out + (size_t)grow * N + bn + wc * 64 + cl;
      orow[0]  = (float)acc[fi][0][r] * (xs * wsc0) + bs0;
      orow[32] = (float)acc[fi][1][r] * (xs * wsc1) + bs1;
    }
  }
}

// ---------------------------------------------------------------------------
extern "C" void kernel_launch(void* const* d_in, const int* in_sizes, int n_in,
                              void* d_out, int out_size, void* d_ws, size_t ws_size,
                              hipStream_t stream) {
  const float* x = (const float*)d_in[0];
  const int* w = (const int*)d_in[1];
  const float* wscale = (const float*)d_in[2];
  const float* bias = (const float*)d_in[3];
  float* out = (float*)d_out;

  const int N = in_sizes[2];                  // 4096
  const long wk = (long)in_sizes[1];          // N*K
  const int K = (int)(wk / N);                // 4096
  const int M = (int)((long)in_sizes[0] / K); // 8192

  int8_t* xq = (int8_t*)d_ws;                       // M*K (fragment layout)
  int8_t* wq = xq + (size_t)M * K;                  // N*K (fragment layout)
  float* xscale = (float*)(wq + (size_t)N * K);     // M floats

  const int QB = 2048;
  quant_x_kernel<<<QB, 256, 0, stream>>>(x, xq, xscale, M, K, QB);

  const long nchunks = (long)N * K / 16;
  pack_w_kernel<<<2048, 256, 0, stream>>>(w, wq, K, nchunks);

  const int nwg = (M / BMg) * (N / BNg);  // 32*16 = 512
  w8a8_gemm_kernel<<<nwg, 512, 0, stream>>>(xq, wq, xscale, wscale, bias,
                                            out, M, N, K);
}